// Round 4
// baseline (304.591 us; speedup 1.0000x reference)
//
#include <hip/hip_runtime.h>

// BNB 8-bit embedding dequant-gather:
//   out[t, :] = (float)q_weight[x[t], :] * (absmax[x[t]] / 127)
// B*S = 32768 tokens, DIM = 1024, VOCAB = 50257.
// Harness widens int8 q_weight to int32 (one int32 per element).
//
// R2 post-mortem: 1-token-per-block version ran ~110 us (~2.4 TB/s) —
// latency-bound: 3-deep dependent load chain, MLP=1 per wave.
// R3/R4: 8 tokens per block -> 8 independent row-gathers in flight per wave.
// R4 fix: __builtin_nontemporal_store needs clang ext_vector_type, not
// HIP_vector_type (float4) — use native vectors.

#define TOKS 8   // tokens per block

typedef float v4f __attribute__((ext_vector_type(4)));
typedef int   v4i __attribute__((ext_vector_type(4)));

__global__ __launch_bounds__(256) void bnb8_embed_kernel(
    const int* __restrict__ x,
    const int* __restrict__ qw,      // widened int8 values, one int32 each
    const float* __restrict__ absmax,
    float* __restrict__ out,
    int n_tokens,
    int dim)
{
    const int t0 = blockIdx.x * TOKS;
    const int e = threadIdx.x << 2;            // element offset within row

    // 8 block-uniform index loads (x fits in L2) -> scalar loads
    int rows[TOKS];
#pragma unroll
    for (int j = 0; j < TOKS; ++j)
        rows[j] = x[t0 + j];

    // 8 independent scale loads (absmax: 200 KB, L2/L3-resident)
    float scale[TOKS];
#pragma unroll
    for (int j = 0; j < TOKS; ++j)
        scale[j] = absmax[rows[j]] * (1.0f / 127.0f);

    // 8 independent 16B gathers per lane -> 8 loads in flight
    v4i q[TOKS];
#pragma unroll
    for (int j = 0; j < TOKS; ++j)
        q[j] = *(const v4i*)(qw + (size_t)rows[j] * (size_t)dim + e);

#pragma unroll
    for (int j = 0; j < TOKS; ++j) {
        v4f o;
        o.x = (float)q[j].x * scale[j];
        o.y = (float)q[j].y * scale[j];
        o.z = (float)q[j].z * scale[j];
        o.w = (float)q[j].w * scale[j];
        v4f* dst = (v4f*)(out + (size_t)(t0 + j) * (size_t)dim + e);
        __builtin_nontemporal_store(o, dst);   // streaming out: don't pollute L2/L3
    }
}

extern "C" void kernel_launch(void* const* d_in, const int* in_sizes, int n_in,
                              void* d_out, int out_size, void* d_ws, size_t ws_size,
                              hipStream_t stream) {
    const int*   x      = (const int*)d_in[0];    // [B*S] int32
    const int*   qw     = (const int*)d_in[1];    // [VOCAB*DIM] int32 (widened int8)
    const float* absmax = (const float*)d_in[2];  // [VOCAB] f32
    float*       out    = (float*)d_out;          // [B*S*DIM] f32

    const int n_tokens = in_sizes[0];             // 32768
    const int dim = out_size / n_tokens;          // 1024
    const int threads = dim / 4;                  // 256 lanes, 4 elems each
    const int blocks = n_tokens / TOKS;           // 4096 (exact: 32768/8)

    bnb8_embed_kernel<<<blocks, threads, 0, stream>>>(x, qw, absmax, out,
                                                      n_tokens, dim);
}